// Round 2
// baseline (162.705 us; speedup 1.0000x reference)
//
#include <hip/hip_runtime.h>
#include <hip/hip_bf16.h>
#include <math.h>

// KAN layer: out = GELU( einsum('bik,ikj->bj', basis, W) + bias ),
//   basis[b,i,k] = x[b,i]^k, B=4096, D=1024, K=5, U=1024.
//
// Round 5: (1) basis_pack ELIMINATED -- the GEMM computes A = powers(x) on
// the fly (x tile load -> f2bf pack -> ds_write), deleting a 50 MB-traffic
// dispatch and halving A-side L2-external bytes. (2) XCD-aware block swizzle:
// each XCD owns an 8x8 (M x N) sub-grid so its x-slice (2 MB) is L2-resident.
// (3) fold kernels merged into w_pack (shuffle-reduce + atomicAdd) + tiny
// b2-init. Dispatches 5 -> 3. GEMM pipeline: 5 LDS buffers (60 KB), B-DMA
// at distance +4, x->reg at +5 (ring-4 static slots), A ds_write at +2,
// one fused "s_waitcnt vmcnt(8) lgkmcnt(0); s_barrier" per K-step.

#define B_DIM 4096
#define D_DIM 1024
#define U_DIM 1024
#define KT2 4096            // GEMM K after dropping k=0 plane
#define NKB 128             // 32-wide k-blocks

typedef unsigned short ushort_t;
typedef __attribute__((ext_vector_type(8))) short bf16x8;   // MFMA A/B frag
typedef __attribute__((ext_vector_type(4))) float f32x4;    // MFMA C/D frag
typedef __attribute__((ext_vector_type(2))) float f32x2;

__device__ __forceinline__ ushort_t f2bf(float f) {
  union { float f; unsigned int u; } v;
  v.f = f;
  unsigned int r = v.u + 0x7FFFu + ((v.u >> 16) & 1u);
  return (ushort_t)(r >> 16);
}

__device__ __forceinline__ void load_lds16(const ushort_t* g, ushort_t* l) {
  __builtin_amdgcn_global_load_lds(
      (const __attribute__((address_space(1))) ushort_t*)g,
      (__attribute__((address_space(3))) ushort_t*)l, 16, 0, 0);
}

__device__ __forceinline__ float gelu_exact(float v) {
  return 0.5f * v * (1.0f + erff(v * 0.70710678118654752f));
}

// packed addr (ushorts) of (row, k): ((row>>4)*NKB + (k>>5))*512
//                                     + (((k>>3)&3)*16 + (row&15))*8 + (k&7)

// ---------------- prep A: b2 = bias (atomics accumulate fold on top) ----------------
__global__ __launch_bounds__(256) void init_b2_kernel(
    const float* __restrict__ bias, float* __restrict__ b2) {
  const int j = blockIdx.x * 256 + threadIdx.x;   // grid.x = 4
  b2[j] = bias[j];
}

// ---------------- prep B: W -> B_packed (planes 1..4) + fold k=0 into b2 ----------------
__global__ __launch_bounds__(256) void w_pack_kernel(
    const float* __restrict__ W, ushort_t* __restrict__ Bp,
    float* __restrict__ b2) {
  const int t    = threadIdx.x;
  const int wave = t >> 6;
  const int lane = t & 63;
  const int kblk = blockIdx.x * 4 + wave;     // 0..127
  const int n16  = blockIdx.y;                // 0..63
  const int jj   = lane & 15;
  const int ko   = lane >> 4;
  const int j    = n16 * 16 + jj;
  const int i0   = kblk * 8 + ko * 2;

  ushort_t o[8];
  float s0 = 0.0f;
#pragma unroll
  for (int t2 = 0; t2 < 2; ++t2) {
    const int i = i0 + t2;
    s0 += W[(size_t)(i * 5) * U_DIM + j];       // k=0 plane (all-ones basis)
#pragma unroll
    for (int e = 0; e < 4; ++e) {
      const int r = i * 5 + e + 1;              // planes 1..4
      o[t2 * 4 + e] = f2bf(W[(size_t)r * U_DIM + j]);
    }
  }
  *(uint4*)(Bp + ((size_t)n16 * NKB + kblk) * 512 + lane * 8) = *(const uint4*)o;
  // reduce the k=0 partial over the 4 ko groups (lanes ^16, ^32), one atomic/jj
  s0 += __shfl_xor(s0, 16, 64);
  s0 += __shfl_xor(s0, 32, 64);
  if (ko == 0) atomicAdd(&b2[j], s0);
}

// ---------------- main GEMM: 64x128 tile, fused basis, 5-buf counted-vmcnt ----------------
// buffer layout: unit u 0..3 = A m16 u (ds_written from x), u 4..11 = B n16
// u-4 (global_load_lds DMA). 12 KB/buffer x 5 = 60 KB. Distances: B-stage
// it+4, x-load it+5 (reg ring of 4, static slots), A-write it+2, compute it.
// Steady fused wait: vmcnt(8) = keep {B(it+1..3), x(it+3..4)} in flight.
__global__ __launch_bounds__(256) void gemm_kernel(
    const float* __restrict__ x, const ushort_t* __restrict__ Bp,
    const float* __restrict__ b2, float* __restrict__ C) {
  __shared__ __align__(16) ushort_t lds[5][12 * 512];   // 5 x 12 KB

  const int tid  = threadIdx.x;
  const int wave = tid >> 6;
  const int lane = tid & 63;
  const int wm   = wave >> 1;             // 0..1 : 32-row half
  const int wn   = wave & 1;              // 0..1 : 64-col half

  // XCD swizzle: linear id = y*8+x, hw XCD = lin&7. Give each XCD a
  // contiguous 8(M) x 8(N) sub-grid -> its x slice (2 MB) stays L2-resident.
  const int lin  = blockIdx.y * 8 + blockIdx.x;
  const int xcd  = lin & 7;
  const int slot = lin >> 3;              // 0..63
  const int mt   = xcd * 8 + (slot & 7);  // 0..63
  const int nt   = slot >> 3;             // 0..7
  const int m16b = mt * 4;
  const int n16b = nt * 8;

  // B staging: s=0,1 -> unit 4 + s*4 + wave (dense 1 KB bursts)
  const ushort_t* gsrcB[2];
  int ldstB[2];
#pragma unroll
  for (int s = 0; s < 2; ++s) {
    const int u = 4 + s * 4 + wave;       // 4..11
    gsrcB[s] = Bp + ((size_t)(n16b + (u - 4)) * NKB) * 512 + lane * 8;
    ldstB[s] = u * 512 + lane * 8;
  }

  // A-path: wave w owns unit w (m16 block m16b+w); lane = (m, ko).
  const int m     = lane & 15;
  const int ko    = lane >> 4;
  const int arow  = (m16b + wave) * 16 + m;
  const float* xsrc = x + (size_t)arow * D_DIM + ko * 2;
  const int ldstA = wave * 512 + lane * 8;

  f32x4 acc[2][4];
  const f32x4 zero = {0.0f, 0.0f, 0.0f, 0.0f};
#pragma unroll
  for (int mf = 0; mf < 2; ++mf)
#pragma unroll
    for (int nf = 0; nf < 4; ++nf) acc[mf][nf] = zero;

  f32x2 xr[4];

#define FENCE asm volatile("" ::: "memory")
#define WAITBAR(N) \
  asm volatile("s_waitcnt vmcnt(" #N ") lgkmcnt(0)\n\ts_barrier" ::: "memory")

#define STAGE_B(bb, it)                                                 \
  do {                                                                  \
    load_lds16(gsrcB[0] + (size_t)(it) * 512, &lds[bb][ldstB[0]]);      \
    load_lds16(gsrcB[1] + (size_t)(it) * 512, &lds[bb][ldstB[1]]);      \
  } while (0)

#define LOADX(sl, it) xr[sl] = *(const f32x2*)(xsrc + (size_t)(it) * 8)

#define WRITEA(bb, sl)                                                  \
  do {                                                                  \
    const float xa = xr[sl][0], xb = xr[sl][1];                         \
    const float xa2 = xa * xa, xb2 = xb * xb;                           \
    ushort_t o[8];                                                      \
    o[0] = f2bf(xa);  o[1] = f2bf(xa2);                                 \
    o[2] = f2bf(xa2 * xa); o[3] = f2bf(xa2 * xa2);                      \
    o[4] = f2bf(xb);  o[5] = f2bf(xb2);                                 \
    o[6] = f2bf(xb2 * xb); o[7] = f2bf(xb2 * xb2);                      \
    *(uint4*)(&lds[bb][ldstA]) = *(const uint4*)o;                      \
  } while (0)

#define COMPUTE(bb)                                                     \
  do {                                                                  \
    bf16x8 a[2], b[4];                                                  \
    _Pragma("unroll")                                                   \
    for (int mf = 0; mf < 2; ++mf)                                      \
      a[mf] = *(const bf16x8*)&lds[bb][(wm * 2 + mf) * 512 + lane * 8]; \
    _Pragma("unroll")                                                   \
    for (int nf = 0; nf < 4; ++nf)                                      \
      b[nf] = *(const bf16x8*)&lds[bb][(4 + wn * 4 + nf) * 512 + lane * 8]; \
    _Pragma("unroll")                                                   \
    for (int mf = 0; mf < 2; ++mf)                                      \
      _Pragma("unroll")                                                 \
      for (int nf = 0; nf < 4; ++nf)                                    \
        acc[mf][nf] = __builtin_amdgcn_mfma_f32_16x16x32_bf16(          \
            a[mf], b[nf], acc[mf][nf], 0, 0, 0);                        \
  } while (0)

  // ---- prologue: A(0),A(1) written; B(0..3) staged; x(2..4) in flight ----
  LOADX(0, 0);
  LOADX(1, 1);
  asm volatile("s_waitcnt vmcnt(0)" ::: "memory");
  WRITEA(0, 0);
  WRITEA(1, 1);
  FENCE;
  LOADX(2, 2); FENCE;
  STAGE_B(0, 0); FENCE;
  LOADX(3, 3); FENCE;
  STAGE_B(1, 1); FENCE;
  LOADX(0, 4); FENCE;
  STAGE_B(2, 2);
  STAGE_B(3, 3);
  // outstanding: [x2, B0ab, x3, B1ab, x4, B2ab, B3ab] = 11; vmcnt(8) at it=0
  // drains oldest 3 = {x2, B0a, B0b} -- exactly what compute(0)/writeA(2) need.

  // ---- main loop it = 0..119 (unroll 4 keeps xr slots static) ----
  int bc = 0, ba = 2, bs = 4;   // it%5, (it+2)%5, (it+4)%5
  for (int base = 0; base < 120; base += 4) {
#pragma unroll
    for (int j = 0; j < 4; ++j) {
      const int it = base + j;
      WAITBAR(8);                       // drains B(it), x(it+2); keeps 8 in flight
      LOADX((j + 1) & 3, it + 5);
      FENCE;
      STAGE_B(bs, it + 4);
      FENCE;
      WRITEA(ba, (j + 2) & 3);
      COMPUTE(bc);
      bc = (bc == 4) ? 0 : bc + 1;
      ba = (ba == 4) ? 0 : ba + 1;
      bs = (bs == 4) ? 0 : bs + 1;
    }
  }

  // ---- tail peel it = 120..127 (literal buffers/slots/counts) ----
  WAITBAR(8);                    // it=120: needs B(120), x(122)
  LOADX(1, 125); FENCE;
  STAGE_B(4, 124); FENCE;
  WRITEA(2, 2);
  COMPUTE(0);

  WAITBAR(8);                    // it=121: needs B(121), x(123)
  LOADX(2, 126); FENCE;
  STAGE_B(0, 125); FENCE;
  WRITEA(3, 3);
  COMPUTE(1);

  WAITBAR(8);                    // it=122: needs B(122), x(124)
  LOADX(3, 127); FENCE;
  STAGE_B(1, 126); FENCE;
  WRITEA(4, 0);
  COMPUTE(2);

  WAITBAR(8);                    // it=123: needs B(123), x(125)
  STAGE_B(2, 127);
  FENCE;
  WRITEA(0, 1);
  COMPUTE(3);

  WAITBAR(7);                    // it=124: needs B(124), x(126)
  WRITEA(1, 2);
  COMPUTE(4);

  WAITBAR(4);                    // it=125: needs B(125), x(127)
  WRITEA(2, 3);
  COMPUTE(0);

  WAITBAR(2);                    // it=126: needs B(126)
  COMPUTE(1);

  WAITBAR(0);                    // it=127: needs B(127)
  COMPUTE(2);

#undef STAGE_B
#undef LOADX
#undef WRITEA
#undef COMPUTE
#undef WAITBAR
#undef FENCE

  // epilogue: C/D map: col = lane&15, row = (lane>>4)*4 + reg
  const int crow0 = m16b * 16 + wm * 32 + (lane >> 4) * 4;
  const int ccol0 = n16b * 16 + wn * 64 + (lane & 15);
#pragma unroll
  for (int nf = 0; nf < 4; ++nf) {
    const int col = ccol0 + nf * 16;
    const float bv = b2[col];
#pragma unroll
    for (int mf = 0; mf < 2; ++mf) {
#pragma unroll
      for (int r = 0; r < 4; ++r) {
        const int row = crow0 + mf * 16 + r;
        C[(size_t)row * U_DIM + col] = gelu_exact(acc[mf][nf][r] + bv);
      }
    }
  }
}

// ---------------- fallback (ws too small): fp32, no workspace ----------------
__global__ void fallback_kernel(const float* __restrict__ x, const float* __restrict__ W,
                                const float* __restrict__ bias, float* __restrict__ out) {
  int j  = blockIdx.x * 256 + threadIdx.x;
  int b0 = blockIdx.y * 16;
  float acc[16];
#pragma unroll
  for (int t = 0; t < 16; ++t) acc[t] = 0.0f;
  for (int i = 0; i < D_DIM; ++i) {
    const float* wr = W + (size_t)i * 5 * U_DIM + j;
    float w0 = wr[0 * U_DIM], w1 = wr[1 * U_DIM], w2 = wr[2 * U_DIM];
    float w3 = wr[3 * U_DIM], w4 = wr[4 * U_DIM];
#pragma unroll
    for (int t = 0; t < 16; ++t) {
      float xv = x[(size_t)(b0 + t) * D_DIM + i];
      float x2 = xv * xv;
      acc[t] += w0 + xv * w1 + x2 * w2 + x2 * xv * w3 + x2 * x2 * w4;
    }
  }
  float bv = bias[j];
#pragma unroll
  for (int t = 0; t < 16; ++t)
    out[(size_t)(b0 + t) * U_DIM + j] = gelu_exact(acc[t] + bv);
}

extern "C" void kernel_launch(void* const* d_in, const int* in_sizes, int n_in,
                              void* d_out, int out_size, void* d_ws, size_t ws_size,
                              hipStream_t stream) {
  const float* x    = (const float*)d_in[0];   // (4096, 1024)
  const float* W    = (const float*)d_in[1];   // (1024, 5, 1024), row r = i*5+k
  const float* bias = (const float*)d_in[2];   // (1024,)
  float* out = (float*)d_out;                  // (4096, 1024) fp32

  const size_t szB = (size_t)U_DIM * KT2 * sizeof(ushort_t);   // 8.39 MB
  const size_t szb = (size_t)U_DIM * sizeof(float);            //    4 KB

  if (ws_size >= szB + szb) {
    ushort_t* Bp = (ushort_t*)d_ws;
    float*    b2 = (float*)((char*)d_ws + szB);
    init_b2_kernel<<<dim3(U_DIM / 256), 256, 0, stream>>>(bias, b2);
    w_pack_kernel<<<dim3(NKB / 4, U_DIM / 16), 256, 0, stream>>>(W, Bp, b2);
    gemm_kernel<<<dim3(U_DIM / 128, B_DIM / 64), 256, 0, stream>>>(x, Bp, b2, out);
  } else {
    fallback_kernel<<<dim3(U_DIM / 256, B_DIM / 16), 256, 0, stream>>>(x, W, bias, out);
  }
}

// Round 3
// 137.056 us; speedup vs baseline: 1.1871x; 1.1871x over previous
//
#include <hip/hip_runtime.h>
#include <hip/hip_bf16.h>
#include <math.h>

// KAN layer: out = GELU( einsum('bik,ikj->bj', basis, W) + bias ),
//   basis[b,i,k] = x[b,i]^k, B=4096, D=1024, K=5, U=1024.
//
// Round 6: REVERT the r5 in-GEMM basis fusion (x-gather + in-loop ds_write
// serialized the pipeline: 60->116us). Back to the proven DMA-only 4-buf
// counted-vmcnt loop (r4, 60.4us), plus:
//  (1) manual x4 unroll, literal buffer indices: ds_read = base VGPR +
//      offset:imm, DMA src = 1 ptr-bump/stream/chunk (+-4KB literal offsets)
//      -- cuts the measured 48% VALUBusy address overhead.
//  (2) XCD-aware bijective swizzle (verified in r5): each XCD owns an 8m x 8n
//      chunk, exactly co-resident on its 32 CUs; Ap slice (4MB) = its L2.
//  (3) fold kernels merged into w_pack (atomicAdd into fold[], zeroed by
//      basis_pack block 0); epilogue adds bias+fold. Dispatches 5 -> 3.

#define B_DIM 4096
#define D_DIM 1024
#define U_DIM 1024
#define KT2 4096            // GEMM K after dropping k=0 plane
#define NKB 128             // 32-wide k-blocks

typedef unsigned short ushort_t;
typedef __attribute__((ext_vector_type(8))) short bf16x8;   // MFMA A/B frag
typedef __attribute__((ext_vector_type(4))) float f32x4;    // MFMA C/D frag

__device__ __forceinline__ ushort_t f2bf(float f) {
  union { float f; unsigned int u; } v;
  v.f = f;
  unsigned int r = v.u + 0x7FFFu + ((v.u >> 16) & 1u);
  return (ushort_t)(r >> 16);
}

__device__ __forceinline__ void load_lds16(const ushort_t* g, ushort_t* l) {
  __builtin_amdgcn_global_load_lds(
      (const __attribute__((address_space(1))) ushort_t*)g,
      (__attribute__((address_space(3))) ushort_t*)l, 16, 0, 0);
}

__device__ __forceinline__ float gelu_exact(float v) {
  return 0.5f * v * (1.0f + erff(v * 0.70710678118654752f));
}

// packed addr (ushorts) of (row, k): ((row>>4)*NKB + (k>>5))*512
//                                     + (((k>>3)&3)*16 + (row&15))*8 + (k&7)

// ---------------- prep 1: x -> A_packed (powers 1..4); block(0,0) zeroes fold ----------------
__global__ __launch_bounds__(256) void basis_pack_kernel(
    const float* __restrict__ x, ushort_t* __restrict__ Ap,
    float* __restrict__ fold) {
  if (blockIdx.x == 0 && blockIdx.y == 0) {
#pragma unroll
    for (int q = 0; q < 4; ++q) fold[q * 256 + threadIdx.x] = 0.0f;
  }
  const int t    = threadIdx.x;
  const int wave = t >> 6;
  const int lane = t & 63;
  const int kblk = blockIdx.x * 4 + wave;     // 0..127
  const int m16  = blockIdx.y;                // 0..255
  const int m    = lane & 15;
  const int ko   = lane >> 4;                 // k-octet 0..3
  const int row  = m16 * 16 + m;
  const int i0   = kblk * 8 + ko * 2;

  const float xa = x[(size_t)row * D_DIM + i0];
  const float xb = x[(size_t)row * D_DIM + i0 + 1];
  const float xa2 = xa * xa, xb2 = xb * xb;
  ushort_t o[8];
  o[0] = f2bf(xa);  o[1] = f2bf(xa2); o[2] = f2bf(xa2 * xa); o[3] = f2bf(xa2 * xa2);
  o[4] = f2bf(xb);  o[5] = f2bf(xb2); o[6] = f2bf(xb2 * xb); o[7] = f2bf(xb2 * xb2);
  *(uint4*)(Ap + ((size_t)m16 * NKB + kblk) * 512 + lane * 8) = *(const uint4*)o;
}

// ---------------- prep 2: W -> B_packed (planes 1..4) + fold k=0 plane ----------------
__global__ __launch_bounds__(256) void w_pack_kernel(
    const float* __restrict__ W, ushort_t* __restrict__ Bp,
    float* __restrict__ fold) {
  const int t    = threadIdx.x;
  const int wave = t >> 6;
  const int lane = t & 63;
  const int kblk = blockIdx.x * 4 + wave;     // 0..127
  const int n16  = blockIdx.y;                // 0..63
  const int jj   = lane & 15;
  const int ko   = lane >> 4;
  const int j    = n16 * 16 + jj;
  const int i0   = kblk * 8 + ko * 2;

  ushort_t o[8];
  float s0 = 0.0f;
#pragma unroll
  for (int t2 = 0; t2 < 2; ++t2) {
    const int i = i0 + t2;
    s0 += W[(size_t)(i * 5) * U_DIM + j];       // k=0 plane (all-ones basis)
#pragma unroll
    for (int e = 0; e < 4; ++e) {
      const int r = i * 5 + e + 1;              // planes 1..4
      o[t2 * 4 + e] = f2bf(W[(size_t)r * U_DIM + j]);
    }
  }
  *(uint4*)(Bp + ((size_t)n16 * NKB + kblk) * 512 + lane * 8) = *(const uint4*)o;
  // reduce k=0 partial over the 4 ko groups (lanes ^16, ^32), one atomic per jj
  s0 += __shfl_xor(s0, 16, 64);
  s0 += __shfl_xor(s0, 32, 64);
  if (ko == 0) atomicAdd(&fold[j], s0);
}

// ---------------- main GEMM: 64x128 tile, BK=32, 4-buf counted-vmcnt, x4 unroll ----------------
// buffer layout: unit u = r (r 0..3 = A m16 r, r 4..11 = B n16 r-4).
// 12 KB per buffer, x4 = 48 KB. Prefetch distance 3, wait vmcnt(6): stages
// it+1, it+2 (2 x 3 loads/thread) stay in flight across the barrier.
__global__ __launch_bounds__(256) void gemm_kernel(
    const ushort_t* __restrict__ Ap, const ushort_t* __restrict__ Bp,
    const float* __restrict__ bias, const float* __restrict__ fold,
    float* __restrict__ C) {
  __shared__ __align__(16) ushort_t lds[4][12 * 512];   // 4 x 12 KB

  const int tid  = threadIdx.x;
  const int wave = tid >> 6;
  const int lane = tid & 63;
  const int wm   = wave >> 1;             // 0..1 : 32-row half
  const int wn   = wave & 1;              // 0..1 : 64-col half

  // XCD swizzle (bijective, 512 = 8 xcd * 64): each XCD owns an 8m x 8n
  // chunk, exactly co-resident on its 32 CUs (2 blocks/CU). Ap slice = 4 MB.
  const int lin  = blockIdx.y * 8 + blockIdx.x;
  const int xcd  = lin & 7;
  const int slot = lin >> 3;              // 0..63
  const int mt   = xcd * 8 + (slot & 7);  // 0..63
  const int nt   = slot >> 3;             // 0..7
  const int m16b = mt * 4;
  const int n16b = nt * 8;

  // staging assignment: s=0..2, unit u = s*4 + wave (dense 1 KB bursts)
  const ushort_t* gcur[3];
  int ldst[3];
#pragma unroll
  for (int s = 0; s < 3; ++s) {
    const int u = s * 4 + wave;           // 0..11
    const ushort_t* base = (u < 4)
        ? Ap + ((size_t)(m16b + u) * NKB) * 512
        : Bp + ((size_t)(n16b + (u - 4)) * NKB) * 512;
    gcur[s] = base + lane * 8;
    ldst[s] = u * 512 + lane * 8;
  }

  f32x4 acc[2][4];
  const f32x4 zero = {0.0f, 0.0f, 0.0f, 0.0f};
#pragma unroll
  for (int mf = 0; mf < 2; ++mf)
#pragma unroll
    for (int nf = 0; nf < 4; ++nf) acc[mf][nf] = zero;

#define WAITBAR(N) \
  asm volatile("s_waitcnt vmcnt(" #N ")\n\ts_barrier" ::: "memory")

// stage k-block at literal ushort-offset REL*512 from the rolling pointer
#define STAGE_REL(bb, rel)                                              \
  do {                                                                  \
    _Pragma("unroll")                                                   \
    for (int s = 0; s < 3; ++s)                                         \
      load_lds16(gcur[s] + (rel) * 512, &lds[bb][ldst[s]]);             \
  } while (0)

#define COMPUTE(bb)                                                     \
  do {                                                                  \
    bf16x8 a[2], b[4];                                                  \
    _Pragma("unroll")                                                   \
    for (int mf = 0; mf < 2; ++mf)                                      \
      a[mf] = *(const bf16x8*)&lds[bb][(wm * 2 + mf) * 512 + lane * 8]; \
    _Pragma("unroll")                                                   \
    for (int nf = 0; nf < 4; ++nf)                                      \
      b[nf] = *(const bf16x8*)&lds[bb][(4 + wn * 4 + nf) * 512 + lane * 8]; \
    _Pragma("unroll")                                                   \
    for (int mf = 0; mf < 2; ++mf)                                      \
      _Pragma("unroll")                                                 \
      for (int nf = 0; nf < 4; ++nf)                                    \
        acc[mf][nf] = __builtin_amdgcn_mfma_f32_16x16x32_bf16(          \
            a[mf], b[nf], acc[mf][nf], 0, 0, 0);                        \
  } while (0)

  // prologue: stage k-blocks 0..2 into buffers 0..2 (9 loads in flight)
  STAGE_REL(0, 0);
  STAGE_REL(1, 1);
  STAGE_REL(2, 2);
#pragma unroll
  for (int s = 0; s < 3; ++s) gcur[s] += 4 * 512;   // rebase: rel 0 == k-block 4

  // main loop, chunks of 4: it = base..base+3 computes buffers 0..3,
  // stages k-blocks base+3..base+6 into buffers 3,0,1,2.
  // Literal rel offsets {-1,0,1,2} (bytes -1024..2048) fold into the global
  // offset imm; one 3-stream pointer bump (+4KB) per chunk.
  for (int base = 0; base < 124; base += 4) {
    WAITBAR(6); STAGE_REL(3, -1); COMPUTE(0);   // stage base+3
    WAITBAR(6); STAGE_REL(0,  0); COMPUTE(1);   // stage base+4
    WAITBAR(6); STAGE_REL(1,  1); COMPUTE(2);   // stage base+5
    WAITBAR(6); STAGE_REL(2,  2); COMPUTE(3);   // stage base+6
#pragma unroll
    for (int s = 0; s < 3; ++s) gcur[s] += 4 * 512;
  }
  // tail: it = 124..127 (gcur rel 0 == k-block 128)
  WAITBAR(6); STAGE_REL(3, -1); COMPUTE(0);     // stage 127
  WAITBAR(6); COMPUTE(1);
  WAITBAR(3); COMPUTE(2);
  WAITBAR(0); COMPUTE(3);
#undef STAGE_REL
#undef COMPUTE
#undef WAITBAR

  // epilogue: C/D map: col = lane&15, row = (lane>>4)*4 + reg
  const int crow0 = m16b * 16 + wm * 32 + (lane >> 4) * 4;
  const int ccol0 = n16b * 16 + wn * 64 + (lane & 15);
#pragma unroll
  for (int nf = 0; nf < 4; ++nf) {
    const int col = ccol0 + nf * 16;
    const float bv = bias[col] + fold[col];
#pragma unroll
    for (int mf = 0; mf < 2; ++mf) {
#pragma unroll
      for (int r = 0; r < 4; ++r) {
        const int row = crow0 + mf * 16 + r;
        C[(size_t)row * U_DIM + col] = gelu_exact(acc[mf][nf][r] + bv);
      }
    }
  }
}

// ---------------- fallback (ws too small): fp32, no workspace ----------------
__global__ void fallback_kernel(const float* __restrict__ x, const float* __restrict__ W,
                                const float* __restrict__ bias, float* __restrict__ out) {
  int j  = blockIdx.x * 256 + threadIdx.x;
  int b0 = blockIdx.y * 16;
  float acc[16];
#pragma unroll
  for (int t = 0; t < 16; ++t) acc[t] = 0.0f;
  for (int i = 0; i < D_DIM; ++i) {
    const float* wr = W + (size_t)i * 5 * U_DIM + j;
    float w0 = wr[0 * U_DIM], w1 = wr[1 * U_DIM], w2 = wr[2 * U_DIM];
    float w3 = wr[3 * U_DIM], w4 = wr[4 * U_DIM];
#pragma unroll
    for (int t = 0; t < 16; ++t) {
      float xv = x[(size_t)(b0 + t) * D_DIM + i];
      float x2 = xv * xv;
      acc[t] += w0 + xv * w1 + x2 * w2 + x2 * xv * w3 + x2 * x2 * w4;
    }
  }
  float bv = bias[j];
#pragma unroll
  for (int t = 0; t < 16; ++t)
    out[(size_t)(b0 + t) * U_DIM + j] = gelu_exact(acc[t] + bv);
}

extern "C" void kernel_launch(void* const* d_in, const int* in_sizes, int n_in,
                              void* d_out, int out_size, void* d_ws, size_t ws_size,
                              hipStream_t stream) {
  const float* x    = (const float*)d_in[0];   // (4096, 1024)
  const float* W    = (const float*)d_in[1];   // (1024, 5, 1024), row r = i*5+k
  const float* bias = (const float*)d_in[2];   // (1024,)
  float* out = (float*)d_out;                  // (4096, 1024) fp32

  const size_t szA = (size_t)B_DIM * KT2 * sizeof(ushort_t);   // 33.55 MB
  const size_t szB = (size_t)U_DIM * KT2 * sizeof(ushort_t);   //  8.39 MB
  const size_t szF = (size_t)U_DIM * sizeof(float);            //    4 KB

  if (ws_size >= szA + szB + szF) {
    ushort_t* Ap   = (ushort_t*)d_ws;
    ushort_t* Bp   = (ushort_t*)((char*)d_ws + szA);
    float*    fld  = (float*)((char*)d_ws + szA + szB);
    basis_pack_kernel<<<dim3(NKB / 4, B_DIM / 16), 256, 0, stream>>>(x, Ap, fld);
    w_pack_kernel<<<dim3(NKB / 4, U_DIM / 16), 256, 0, stream>>>(W, Bp, fld);
    gemm_kernel<<<dim3(U_DIM / 128, B_DIM / 64), 256, 0, stream>>>(Ap, Bp, bias, fld, out);
  } else {
    fallback_kernel<<<dim3(U_DIM / 256, B_DIM / 16), 256, 0, stream>>>(x, W, bias, out);
  }
}